// Round 9
// baseline (759.547 us; speedup 1.0000x reference)
//
#include <hip/hip_runtime.h>
#include <cstdint>
#include <cstddef>

// VQ nearest-codebook, two-phase:
//   P1: fp16 MFMA approx scores -> per-row candidate set (superset, margin-sound).
//       R9: BK=32 double-buffered 2-phase pipeline (T3 minimum recipe):
//       STAGE(next) issued BEFORE ds_read+MFMA(cur), one barrier per kc-step
//       -> the barrier's vmcnt(0) drain is covered by compute. Statically
//       distinct Ah0/Ah1/Bh0/Bh1 (kc unrolled x2) so alias analysis keeps
//       the stage ahead of the reads. LDS 49 KB, 16 waves/CU kept (R8).
//   P2: select (4-segment merge + singleton decide) -> dense pair worklist
//       -> packed u64 atomicMin argmin -> block-per-row fallback net -> gather.
constexpr int N_ROWS = 32768;
constexpr int KCODES = 8192;
constexpr int DIMS   = 512;
constexpr int NSEG   = 4;         // codebook quarters (one per block column)
constexpr int SEGC   = KCODES / NSEG;
constexpr int CAND   = 32;
constexpr float MARGIN = 1e-3f;   // approx err ~2e-4/side incl fp16 store slop
constexpr int PAIR_CAP = 1 << 18; // 256K pairs (post-filter expectation ~75K)
constexpr unsigned SENT = 0xFFFFFFFFu;
constexpr int NT  = SEGC / 128;   // 16 code-tiles per segment
constexpr int NKC = DIMS / 32;    // 16 K-steps (BK=32)

typedef _Float16 half8 __attribute__((ext_vector_type(8)));
typedef float    f32x4 __attribute__((ext_vector_type(4)));

// async global->LDS, 16B per lane; LDS dest is wave-uniform base + lane*16
__device__ __forceinline__ void gload16(const void* g, void* l) {
  __builtin_amdgcn_global_load_lds(
      (const __attribute__((address_space(1))) void*)g,
      (__attribute__((address_space(3))) void*)l, 16, 0, 0);
}

// packed candidate: high16 = fp16 bits of delta (= csq - 2*z.c approx),
// low16 = 13-bit global code id. Delta compares equal-offset per row (zsq).
__device__ __forceinline__ unsigned pack_ds(float d, int code) {
  union { _Float16 h; unsigned short u; } c; c.h = (_Float16)d;
  return ((unsigned)c.u << 16) | (unsigned)code;
}
__device__ __forceinline__ float unpack_d(unsigned e) {
  union { _Float16 h; unsigned short u; } c; c.u = (unsigned short)(e >> 16);
  return (float)c.h;
}

// ---- bitwise replica of np.sum(x*x,-1) fp32 pairwise (AVX512 npyv tree) ----
__global__ __launch_bounds__(256) void rowsq_kernel(const float* __restrict__ x,
                                                    float* __restrict__ out) {
  int row  = (blockIdx.x * 256 + threadIdx.x) >> 6;  // one row per wave
  int lane = threadIdx.x & 63;
  int blk = lane >> 4, l16 = lane & 15;
  const float* p = x + (size_t)row * DIMS + blk * 128 + l16;
  float A[8];
  #pragma unroll
  for (int j = 0; j < 8; ++j) { float v = p[16 * j]; A[j] = __fmul_rn(v, v); }
  float u = __fadd_rn(__fadd_rn(__fadd_rn(A[0], A[1]), __fadd_rn(A[2], A[3])),
                      __fadd_rn(__fadd_rn(A[4], A[5]), __fadd_rn(A[6], A[7])));
  u = __fadd_rn(u, __shfl_xor(u, 8, 64));
  u = __fadd_rn(u, __shfl_xor(u, 4, 64));
  u = __fadd_rn(u, __shfl_xor(u, 2, 64));
  u = __fadd_rn(u, __shfl_xor(u, 1, 64));
  u = __fadd_rn(u, __shfl_xor(u, 16, 64));
  u = __fadd_rn(u, __shfl_xor(u, 32, 64));
  if (lane == 0) out[row] = u;
}

// ---- fp32 -> fp16 converters (codebook scaled by 2^11, exact pow2) ----
__global__ __launch_bounds__(256) void cvt_cb_kernel(const float* __restrict__ cb,
                                                     _Float16* __restrict__ chs) {
  int i = blockIdx.x * 256 + threadIdx.x;          // 4 elements per thread
  float4 v = ((const float4*)cb)[i];
  union { _Float16 h[4]; uint2 u; } p;
  p.h[0] = (_Float16)(v.x * 2048.0f);
  p.h[1] = (_Float16)(v.y * 2048.0f);
  p.h[2] = (_Float16)(v.z * 2048.0f);
  p.h[3] = (_Float16)(v.w * 2048.0f);
  ((uint2*)chs)[i] = p.u;
}
__global__ __launch_bounds__(256) void cvt_z_kernel(const float* __restrict__ z,
                                                    _Float16* __restrict__ zh) {
  int i = blockIdx.x * 256 + threadIdx.x;
  float4 v = ((const float4*)z)[i];
  union { _Float16 h[4]; uint2 u; } p;
  p.h[0] = (_Float16)v.x; p.h[1] = (_Float16)v.y;
  p.h[2] = (_Float16)v.z; p.h[3] = (_Float16)v.w;
  ((uint2*)zh)[i] = p.u;
}

// ---- Phase 1: 128x128 MFMA tiles; double-buffered BK=32 pipeline ----
// LDS tile: [128 rows][32 halfs] = 64B/row, linear. Storage rule:
//   storage[row][slot] = logical[row][slot ^ (row&3)]   (slot = 16B unit)
// gload_lds writes linearly (wave-uniform base + lane*16), so the SOURCE
// address carries the inverse swizzle; ds_read applies the same XOR.
// 8 waves, 2x4 grid: wave (wm,wn) owns rows [wm*64,+64) x cols [wn*32,+32).
template <bool ZH>
__global__ __launch_bounds__(512, 4) void vq_mfma_kernel(
    const float* __restrict__ z, const _Float16* __restrict__ zh,
    const _Float16* __restrict__ chs, const float* __restrict__ csq,
    unsigned* __restrict__ cand_g, int* __restrict__ cnt_g) {
  __shared__ __align__(16) _Float16 Ah0[128 * 32];  // 8 KB each
  __shared__ __align__(16) _Float16 Ah1[128 * 32];
  __shared__ __align__(16) _Float16 Bh0[128 * 32];
  __shared__ __align__(16) _Float16 Bh1[128 * 32];
  __shared__ unsigned rowmin_u[128];   // key = float_as_uint(delta + 4.0f) > 0
  __shared__ int cnt[128];
  __shared__ unsigned char dropped[128];
  __shared__ unsigned cand[128 * CAND];             // 16 KB

  const int tid  = threadIdx.x;
  const int seg  = blockIdx.x & (NSEG - 1);
  const int m0   = (blockIdx.x >> 2) * 128;
  const int nt0  = seg * SEGC;
  const int wave = tid >> 6, lane = tid & 63;
  const int wm = wave >> 2, wn = wave & 3;     // 2x4 wave grid of 64x32
  const int q = lane >> 4, r = lane & 15;

  // staging geometry: wave stages rows [wave*16,+16); lane -> (row, 16B slot)
  const int srow = lane >> 2;                  // row within wave strip
  const int scol = (((lane & 3) ^ (srow & 3)) << 4);  // inverse-swz byte-in-row
  const int rdoff = ((q * 16) ^ ((r & 3) << 4));      // read-side XOR

  if (tid < 128) { rowmin_u[tid] = 0x7f800000u; cnt[tid] = 0; dropped[tid] = 0; }

  // ---- stage helpers (dest pointers wave-uniform; HW adds lane*16) ----
  auto stageA = [&](_Float16* Adst, int kc2) {
    if (ZH) {
      gload16((const char*)zh +
                  ((size_t)(m0 + wave * 16 + srow) * DIMS + kc2 * 32) * 2 + scol,
              (char*)Adst + wave * 1024);
    } else {   // convert-on-the-fly, swizzled VGPR store; 512 thr = 512 chunks
      const int rw = tid >> 2, cs = tid & 3;
      const float* src = z + (size_t)(m0 + rw) * DIMS + kc2 * 32 +
                         ((cs ^ (rw & 3)) << 3);
      float4 v0 = ((const float4*)src)[0], v1 = ((const float4*)src)[1];
      union { _Float16 h[8]; uint4 u; } p;
      p.h[0] = (_Float16)v0.x; p.h[1] = (_Float16)v0.y;
      p.h[2] = (_Float16)v0.z; p.h[3] = (_Float16)v0.w;
      p.h[4] = (_Float16)v1.x; p.h[5] = (_Float16)v1.y;
      p.h[6] = (_Float16)v1.z; p.h[7] = (_Float16)v1.w;
      *(uint4*)((char*)Adst + rw * 64 + cs * 16) = p.u;
    }
  };
  auto stageB = [&](_Float16* Bdst, int nt2, int kc2) {
    gload16((const char*)chs +
                ((size_t)(nt2 + wave * 16 + srow) * DIMS + kc2 * 32) * 2 + scol,
            (char*)Bdst + wave * 1024);
  };

  f32x4 acc[4][2];
  // prologue: stage (t=0, kc=0) into buffer 0
  stageA(Ah0, 0);
  stageB(Bh0, nt0, 0);
  __syncthreads();   // drains vmcnt(0): buffer 0 ready (also covers LDS init)

  for (int t = 0; t < NT; ++t) {
    const int nt = nt0 + t * 128;
    #pragma unroll
    for (int mf = 0; mf < 4; ++mf)
      #pragma unroll
      for (int nf = 0; nf < 2; ++nf) acc[mf][nf] = (f32x4){0.f, 0.f, 0.f, 0.f};

    #pragma unroll 1
    for (int kc = 0; kc < NKC; kc += 2) {
      // ---- phase A: stage next into buf1, compute from buf0 ----
      {
        const int flat = t * NKC + kc + 1;
        if (flat < NT * NKC) {
          const int t2 = flat >> 4, kc2 = flat & 15;
          stageA(Ah1, kc2);
          stageB(Bh1, nt0 + t2 * 128, kc2);
        }
      }
      {
        half8 af[4], bf[2];
        #pragma unroll
        for (int mf = 0; mf < 4; ++mf)
          af[mf] = *(const half8*)((const char*)Ah0 +
                     (wm * 64 + mf * 16 + r) * 64 + rdoff);
        #pragma unroll
        for (int nf = 0; nf < 2; ++nf)
          bf[nf] = *(const half8*)((const char*)Bh0 +
                     (wn * 32 + nf * 16 + r) * 64 + rdoff);
        #pragma unroll
        for (int mf = 0; mf < 4; ++mf)
          #pragma unroll
          for (int nf = 0; nf < 2; ++nf)
            acc[mf][nf] = __builtin_amdgcn_mfma_f32_16x16x32_f16(
                af[mf], bf[nf], acc[mf][nf], 0, 0, 0);
      }
      __syncthreads();   // vmcnt(0) drain covered by the MFMA phase above
      // ---- phase B: stage next into buf0, compute from buf1 ----
      {
        const int flat = t * NKC + kc + 2;
        if (flat < NT * NKC) {
          const int t2 = flat >> 4, kc2 = flat & 15;
          stageA(Ah0, kc2);
          stageB(Bh0, nt0 + t2 * 128, kc2);
        }
      }
      {
        half8 af[4], bf[2];
        #pragma unroll
        for (int mf = 0; mf < 4; ++mf)
          af[mf] = *(const half8*)((const char*)Ah1 +
                     (wm * 64 + mf * 16 + r) * 64 + rdoff);
        #pragma unroll
        for (int nf = 0; nf < 2; ++nf)
          bf[nf] = *(const half8*)((const char*)Bh1 +
                     (wn * 32 + nf * 16 + r) * 64 + rdoff);
        #pragma unroll
        for (int mf = 0; mf < 4; ++mf)
          #pragma unroll
          for (int nf = 0; nf < 2; ++nf)
            acc[mf][nf] = __builtin_amdgcn_mfma_f32_16x16x32_f16(
                af[mf], bf[nf], acc[mf][nf], 0, 0, 0);
      }
      __syncthreads();
    }

    // ---- epilogue on delta = fl(csq - acc*2^-10)  (== sv - zsq, tiny mag,
    //      so fp32 rounding ~1e-8 and fp16 storage ~3e-5 -- margin-safe).
    //      C/D layout: row=q*4+reg, col=r.
    float cs[2];
    #pragma unroll
    for (int nf = 0; nf < 2; ++nf) cs[nf] = csq[nt + wn * 32 + nf * 16 + r];
    float m4[4][4];      // [mf][reg] lane-local min over nf
    #pragma unroll
    for (int mf = 0; mf < 4; ++mf)
      #pragma unroll
      for (int reg = 0; reg < 4; ++reg) {
        float mn = INFINITY;
        #pragma unroll
        for (int nf = 0; nf < 2; ++nf)
          mn = fminf(mn, __fmaf_rn(-0.0009765625f, acc[mf][nf][reg], cs[nf]));
        m4[mf][reg] = mn;
      }
    #pragma unroll
    for (int mf = 0; mf < 4; ++mf)
      #pragma unroll
      for (int reg = 0; reg < 4; ++reg) {
        float v = m4[mf][reg];
        v = fminf(v, __shfl_xor(v, 1, 64));
        v = fminf(v, __shfl_xor(v, 2, 64));
        v = fminf(v, __shfl_xor(v, 4, 64));
        v = fminf(v, __shfl_xor(v, 8, 64));
        m4[mf][reg] = v;
      }
    if (r == 0) {
      #pragma unroll
      for (int mf = 0; mf < 4; ++mf)
        #pragma unroll
        for (int reg = 0; reg < 4; ++reg)
          atomicMin(&rowmin_u[wm * 64 + mf * 16 + q * 4 + reg],
                    __float_as_uint(m4[mf][reg] + 4.0f));  // delta+4 > 0 always
    }
    __syncthreads();   // tile-min includes ALL waves before thresholding
    #pragma unroll
    for (int mf = 0; mf < 4; ++mf)
      #pragma unroll
      for (int reg = 0; reg < 4; ++reg) {
        const int row = wm * 64 + mf * 16 + q * 4 + reg;
        float thr = __uint_as_float(rowmin_u[row]) - 4.0f + MARGIN;
        #pragma unroll
        for (int nf = 0; nf < 2; ++nf) {
          float d = __fmaf_rn(-0.0009765625f, acc[mf][nf][reg], cs[nf]);
          if (d <= thr) {
            int slot = atomicAdd(&cnt[row], 1);
            if (slot < CAND)
              cand[row * CAND + slot] = pack_ds(d, nt + wn * 32 + nf * 16 + r);
          }
        }
      }
    // ---- periodic compaction: re-filter vs the tightened min so the raw
    //      counter never creeps past CAND; drop flag only on a real discard.
    if ((t & 1) == 1 || t == (NT - 1)) {
      __syncthreads();   // all appends for this tile visible
      if (tid < 128) {
        const int raw = cnt[tid];
        const int m = raw < CAND ? raw : CAND;
        if (raw > CAND) dropped[tid] = 1;
        const float thr = __uint_as_float(rowmin_u[tid]) - 4.0f + MARGIN;
        int k = 0;
        for (int i = 0; i < m; ++i) {
          unsigned e = cand[tid * CAND + i];
          if (unpack_d(e) <= thr) cand[tid * CAND + k++] = e;
        }
        cnt[tid] = k;
      }
      __syncthreads();
    }
  }
  __syncthreads();
  if (tid < 128)
    cnt_g[(size_t)seg * N_ROWS + m0 + tid] = dropped[tid] ? (CAND + 1) : cnt[tid];
  for (int i = tid; i < 128 * CAND; i += 512)
    cand_g[((size_t)seg * N_ROWS + m0 + i / CAND) * CAND + (i % CAND)] = cand[i];
}

// ---- exact bitwise-np score (R2-verified): dual-panel seq FMA chain ----
__device__ __forceinline__ float exact_q(const float* zr, const float* cr,
                                         float zsr, float csr) {
  float s1 = 0.f;
  for (int k = 0; k < 384; k += 8) {
    float4 a0 = *(const float4*)(zr + k), a1 = *(const float4*)(zr + k + 4);
    float4 b0 = *(const float4*)(cr + k), b1 = *(const float4*)(cr + k + 4);
    s1 = __fmaf_rn(a0.x, b0.x, s1); s1 = __fmaf_rn(a0.y, b0.y, s1);
    s1 = __fmaf_rn(a0.z, b0.z, s1); s1 = __fmaf_rn(a0.w, b0.w, s1);
    s1 = __fmaf_rn(a1.x, b1.x, s1); s1 = __fmaf_rn(a1.y, b1.y, s1);
    s1 = __fmaf_rn(a1.z, b1.z, s1); s1 = __fmaf_rn(a1.w, b1.w, s1);
  }
  float s2 = 0.f;
  for (int k = 384; k < 512; k += 8) {
    float4 a0 = *(const float4*)(zr + k), a1 = *(const float4*)(zr + k + 4);
    float4 b0 = *(const float4*)(cr + k), b1 = *(const float4*)(cr + k + 4);
    s2 = __fmaf_rn(a0.x, b0.x, s2); s2 = __fmaf_rn(a0.y, b0.y, s2);
    s2 = __fmaf_rn(a0.z, b0.z, s2); s2 = __fmaf_rn(a0.w, b0.w, s2);
    s2 = __fmaf_rn(a1.x, b1.x, s2); s2 = __fmaf_rn(a1.y, b1.y, s2);
    s2 = __fmaf_rn(a1.z, b1.z, s2); s2 = __fmaf_rn(a1.w, b1.w, s2);
  }
  float cross = __fadd_rn(s1, s2);                 // fl(S1 + S2)
  return __fadd_rn(__fmaf_rn(-2.f, cross, zsr), csr);
}

// ---- Phase 2a: 4-segment merge. Global approx-min filter; singleton rows
//      decided free (competitors provably > margin away); rest -> pair list.
__global__ __launch_bounds__(256) void select_kernel(
    const int* __restrict__ cnt_g, const unsigned* __restrict__ cand_g,
    unsigned long long* __restrict__ best, unsigned* __restrict__ pairs,
    int* __restrict__ meta, int* __restrict__ ovf) {
  const int row  = blockIdx.x * 256 + threadIdx.x;
  const int lane = threadIdx.x & 63;
  int c[NSEG]; bool over = false; int tot = 0;
  #pragma unroll
  for (int s = 0; s < NSEG; ++s) {
    c[s] = cnt_g[(size_t)s * N_ROWS + row];
    if (c[s] > CAND) over = true;
    tot += c[s];
  }
  if (tot == 0) over = true;
  unsigned long long bkey = ~0ULL;
  int need = 0;
  float thr = 0.f;
  if (!over) {
    float gm = INFINITY;
    #pragma unroll
    for (int s = 0; s < NSEG; ++s)
      for (int j = 0; j < c[s]; ++j)
        gm = fminf(gm, unpack_d(cand_g[((size_t)s * N_ROWS + row) * CAND + j]));
    thr = gm + MARGIN;
    int k = 0; unsigned first = 0;
    #pragma unroll
    for (int s = 0; s < NSEG; ++s)
      for (int j = 0; j < c[s]; ++j) {
        unsigned e = cand_g[((size_t)s * N_ROWS + row) * CAND + j];
        if (unpack_d(e) <= thr) { if (k == 0) first = e; ++k; }
      }
    if (k == 1) bkey = (unsigned long long)(first & 0x1FFFu);  // decided
    else need = k;
  }
  best[row] = bkey;
  // wave-aggregated worklist allocation (1 atomic per wave)
  int pre = need;
  #pragma unroll
  for (int off = 1; off < 64; off <<= 1) {
    int v = __shfl_up(pre, off, 64);
    if (lane >= off) pre += v;
  }
  int wtot = __shfl(pre, 63, 64);
  int base = 0;
  if (lane == 63 && wtot > 0) base = atomicAdd(&meta[0], wtot);
  base = __shfl(base, 63, 64);
  const int my0 = base + pre - need;              // exclusive prefix
  bool row_ovf = over;
  if (need > 0) {
    if (my0 + need > PAIR_CAP) {
      row_ovf = true;                             // fallback handles this row
      for (int j = 0; j < need; ++j) {            // sentinel allocated slots
        int s = my0 + j;
        if (s < PAIR_CAP) pairs[s] = SENT;
      }
    } else {
      int kk = 0;
      #pragma unroll
      for (int s = 0; s < NSEG; ++s)
        for (int j = 0; j < c[s]; ++j) {
          unsigned e = cand_g[((size_t)s * N_ROWS + row) * CAND + j];
          if (unpack_d(e) <= thr)
            pairs[my0 + kk++] = ((unsigned)row << 13) | (e & 0x1FFFu);
        }
    }
  }
  if (row_ovf) { int s = atomicAdd(&meta[1], 1); ovf[s] = row; }
}

// ---- Phase 2b: dense exact rescore, one lane per (row,code) pair.
//      d2 > 0 always (zsq ~ 512) so uint order == float order; packed key
//      (q_bits<<32)|code -> atomicMin = argmin with lowest-index tie-break.
__global__ __launch_bounds__(256) void pairs_kernel(
    const float* __restrict__ z, const float* __restrict__ cb,
    const float* __restrict__ zsq, const float* __restrict__ csq,
    const unsigned* __restrict__ pairs, const int* __restrict__ meta,
    unsigned long long* __restrict__ best) {
  int n = meta[0];
  if (n > PAIR_CAP) n = PAIR_CAP;
  const int i = blockIdx.x * 256 + threadIdx.x;
  if (i >= n) return;
  const unsigned p = pairs[i];
  if (p == SENT) return;                          // unfilled overflow slot
  const int row = (int)(p >> 13), code = (int)(p & 8191u);
  const float qv = exact_q(z + (size_t)row * DIMS, cb + (size_t)code * DIMS,
                           zsq[row], csq[code]);
  const unsigned long long key =
      ((unsigned long long)__float_as_uint(qv) << 32) | (unsigned)code;
  atomicMin(&best[row], key);
}

// ---- Phase 2c: overflow net, one BLOCK per row.
//      Pass A: coalesced approx scan (8-lane groups, fp32 tree dot), scores
//              to LDS, block min.  Pass B: exact_q within min + 5e-4.
__global__ __launch_bounds__(256) void fallback_kernel(
    const float* __restrict__ z, const float* __restrict__ cb,
    const float* __restrict__ zsq, const float* __restrict__ csq,
    const int* __restrict__ ovf, const int* __restrict__ meta,
    unsigned long long* __restrict__ best) {
  __shared__ float sc[KCODES];     // 32 KB approx deltas
  __shared__ float zrow[DIMS];     // 2 KB
  __shared__ unsigned bmin;
  const int n = meta[1];
  for (int wi = blockIdx.x; wi < n; wi += gridDim.x) {
    const int row = ovf[wi];
    for (int i = threadIdx.x; i < DIMS; i += 256)
      zrow[i] = z[(size_t)row * DIMS + i];
    if (threadIdx.x == 0) bmin = 0x7f800000u;
    __syncthreads();
    const int g = threadIdx.x >> 3;       // 32 groups of 8 lanes
    const int j = threadIdx.x & 7;
    float lmin = INFINITY;
    for (int c = g; c < KCODES; c += 32) {
      const float* cr = cb + (size_t)c * DIMS;
      float s = 0.f;
      #pragma unroll
      for (int i = 0; i < 16; ++i) {      // 64 dims per lane, 128B/group/step
        float4 a = *(const float4*)(&zrow[j * 4 + i * 32]);
        float4 b = *(const float4*)(cr + j * 4 + i * 32);
        s = __fmaf_rn(a.x, b.x, s); s = __fmaf_rn(a.y, b.y, s);
        s = __fmaf_rn(a.z, b.z, s); s = __fmaf_rn(a.w, b.w, s);
      }
      s += __shfl_xor(s, 1, 64);          // butterfly within 8-lane group
      s += __shfl_xor(s, 2, 64);
      s += __shfl_xor(s, 4, 64);
      float d = __fmaf_rn(-2.f, s, csq[c]);
      if (j == 0) sc[c] = d;
      lmin = fminf(lmin, d);
    }
    atomicMin(&bmin, __float_as_uint(lmin + 4.0f));   // delta+4 > 0
    __syncthreads();
    const float thr = __uint_as_float(bmin) - 4.0f + 5e-4f;
    const float zsr = zsq[row];
    const float* zr = z + (size_t)row * DIMS;
    for (int c = threadIdx.x; c < KCODES; c += 256) {
      if (sc[c] <= thr) {
        float qv = exact_q(zr, cb + (size_t)c * DIMS, zsr, csq[c]);
        unsigned long long key =
            ((unsigned long long)__float_as_uint(qv) << 32) | (unsigned)c;
        atomicMin(&best[row], key);
      }
    }
    __syncthreads();   // before next row reuses LDS
  }
}

// ---- Phase 2d: coalesced gather of winner rows + index write ----
__global__ __launch_bounds__(256) void gather_kernel(
    const float* __restrict__ cb, const unsigned long long* __restrict__ best,
    float* __restrict__ zq, float* __restrict__ idx_out) {
  const int wave = threadIdx.x >> 6, lane = threadIdx.x & 63;
  const int row = blockIdx.x * 4 + wave;
  const int code = (int)(unsigned)(best[row] & 0xFFFFFFFFu);
  if (lane == 0) idx_out[row] = (float)code;
  const float4* cbv = (const float4*)(cb + (size_t)code * DIMS);
  float4* zqv = (float4*)(zq + (size_t)row * DIMS);
  zqv[lane]      = cbv[lane];
  zqv[lane + 64] = cbv[lane + 64];
}

extern "C" void kernel_launch(void* const* d_in, const int* in_sizes, int n_in,
                              void* d_out, int out_size, void* d_ws, size_t ws_size,
                              hipStream_t stream) {
  const float* z  = (const float*)d_in[0];
  const float* cb = (const float*)d_in[1];
  float* out     = (float*)d_out;
  float* zq      = out;
  float* idx_out = out + (size_t)N_ROWS * DIMS;

  // workspace layout (all chunks 256B-multiples)
  char* w = (char*)d_ws;
  _Float16* cbh = (_Float16*)w;            w += (size_t)KCODES * DIMS * 2;   // 8 MB
  float* zsq = (float*)w;                  w += (size_t)N_ROWS * 4;          // 128 KB
  float* csq = (float*)w;                  w += (size_t)KCODES * 4;          // 32 KB
  int* cnt_g = (int*)w;                    w += (size_t)NSEG * N_ROWS * 4;   // 512 KB
  unsigned* cand_g = (unsigned*)w;         w += (size_t)NSEG * N_ROWS * CAND * 4; // 16MB
  unsigned long long* best = (unsigned long long*)w; w += (size_t)N_ROWS * 8;  // 256 KB
  unsigned* pairs = (unsigned*)w;          w += (size_t)PAIR_CAP * 4;        // 1 MB
  int* meta = (int*)w;                     w += 256;                         // counters
  int* ovf = (int*)w;                      w += (size_t)N_ROWS * 4;          // 128 KB
  _Float16* zh = (_Float16*)w;             w += (size_t)N_ROWS * DIMS * 2;   // 32 MB
  bool use_zh = ((size_t)(w - (char*)d_ws) <= ws_size);

  hipMemsetAsync(meta, 0, 256, stream);

  rowsq_kernel<<<N_ROWS / 4, 256, 0, stream>>>(z, zsq);
  rowsq_kernel<<<KCODES / 4, 256, 0, stream>>>(cb, csq);
  cvt_cb_kernel<<<KCODES * DIMS / 1024, 256, 0, stream>>>(cb, cbh);
  if (use_zh) {
    cvt_z_kernel<<<N_ROWS * DIMS / 1024, 256, 0, stream>>>(z, zh);
    vq_mfma_kernel<true><<<(N_ROWS / 128) * NSEG, 512, 0, stream>>>(
        z, zh, cbh, csq, cand_g, cnt_g);
  } else {
    vq_mfma_kernel<false><<<(N_ROWS / 128) * NSEG, 512, 0, stream>>>(
        z, nullptr, cbh, csq, cand_g, cnt_g);
  }
  select_kernel<<<N_ROWS / 256, 256, 0, stream>>>(cnt_g, cand_g, best, pairs,
                                                  meta, ovf);
  pairs_kernel<<<PAIR_CAP / 256, 256, 0, stream>>>(z, cb, zsq, csq, pairs,
                                                   meta, best);
  fallback_kernel<<<512, 256, 0, stream>>>(z, cb, zsq, csq, ovf, meta, best);
  gather_kernel<<<N_ROWS / 4, 256, 0, stream>>>(cb, best, zq, idx_out);
}

// Round 10
// 726.327 us; speedup vs baseline: 1.0457x; 1.0457x over previous
//
#include <hip/hip_runtime.h>
#include <cstdint>
#include <cstddef>

// VQ nearest-codebook, two-phase:
//   P1: fp16 MFMA approx scores -> per-row candidate set (superset, margin-sound).
//       R10: R9's BK=32 double-buffered 2-phase pipeline with the LDS swizzle
//       key CORRECTED for 64B rows: bank-half = row&1, so the slot XOR key is
//       (row>>1)&3, not row&3 (R9's bug -> 11x bank conflicts masked the
//       pipeline gain). Same key on gload source, ds_read, and cvt path.
//   P2: select (4-segment merge + singleton decide) -> dense pair worklist
//       -> packed u64 atomicMin argmin -> block-per-row fallback net -> gather.
constexpr int N_ROWS = 32768;
constexpr int KCODES = 8192;
constexpr int DIMS   = 512;
constexpr int NSEG   = 4;         // codebook quarters (one per block column)
constexpr int SEGC   = KCODES / NSEG;
constexpr int CAND   = 32;
constexpr float MARGIN = 1e-3f;   // approx err ~2e-4/side incl fp16 store slop
constexpr int PAIR_CAP = 1 << 18; // 256K pairs (post-filter expectation ~75K)
constexpr unsigned SENT = 0xFFFFFFFFu;
constexpr int NT  = SEGC / 128;   // 16 code-tiles per segment
constexpr int NKC = DIMS / 32;    // 16 K-steps (BK=32)

typedef _Float16 half8 __attribute__((ext_vector_type(8)));
typedef float    f32x4 __attribute__((ext_vector_type(4)));

// async global->LDS, 16B per lane; LDS dest is wave-uniform base + lane*16
__device__ __forceinline__ void gload16(const void* g, void* l) {
  __builtin_amdgcn_global_load_lds(
      (const __attribute__((address_space(1))) void*)g,
      (__attribute__((address_space(3))) void*)l, 16, 0, 0);
}

// packed candidate: high16 = fp16 bits of delta (= csq - 2*z.c approx),
// low16 = 13-bit global code id. Delta compares equal-offset per row (zsq).
__device__ __forceinline__ unsigned pack_ds(float d, int code) {
  union { _Float16 h; unsigned short u; } c; c.h = (_Float16)d;
  return ((unsigned)c.u << 16) | (unsigned)code;
}
__device__ __forceinline__ float unpack_d(unsigned e) {
  union { _Float16 h; unsigned short u; } c; c.u = (unsigned short)(e >> 16);
  return (float)c.h;
}

// ---- bitwise replica of np.sum(x*x,-1) fp32 pairwise (AVX512 npyv tree) ----
__global__ __launch_bounds__(256) void rowsq_kernel(const float* __restrict__ x,
                                                    float* __restrict__ out) {
  int row  = (blockIdx.x * 256 + threadIdx.x) >> 6;  // one row per wave
  int lane = threadIdx.x & 63;
  int blk = lane >> 4, l16 = lane & 15;
  const float* p = x + (size_t)row * DIMS + blk * 128 + l16;
  float A[8];
  #pragma unroll
  for (int j = 0; j < 8; ++j) { float v = p[16 * j]; A[j] = __fmul_rn(v, v); }
  float u = __fadd_rn(__fadd_rn(__fadd_rn(A[0], A[1]), __fadd_rn(A[2], A[3])),
                      __fadd_rn(__fadd_rn(A[4], A[5]), __fadd_rn(A[6], A[7])));
  u = __fadd_rn(u, __shfl_xor(u, 8, 64));
  u = __fadd_rn(u, __shfl_xor(u, 4, 64));
  u = __fadd_rn(u, __shfl_xor(u, 2, 64));
  u = __fadd_rn(u, __shfl_xor(u, 1, 64));
  u = __fadd_rn(u, __shfl_xor(u, 16, 64));
  u = __fadd_rn(u, __shfl_xor(u, 32, 64));
  if (lane == 0) out[row] = u;
}

// ---- fp32 -> fp16 converters (codebook scaled by 2^11, exact pow2) ----
__global__ __launch_bounds__(256) void cvt_cb_kernel(const float* __restrict__ cb,
                                                     _Float16* __restrict__ chs) {
  int i = blockIdx.x * 256 + threadIdx.x;          // 4 elements per thread
  float4 v = ((const float4*)cb)[i];
  union { _Float16 h[4]; uint2 u; } p;
  p.h[0] = (_Float16)(v.x * 2048.0f);
  p.h[1] = (_Float16)(v.y * 2048.0f);
  p.h[2] = (_Float16)(v.z * 2048.0f);
  p.h[3] = (_Float16)(v.w * 2048.0f);
  ((uint2*)chs)[i] = p.u;
}
__global__ __launch_bounds__(256) void cvt_z_kernel(const float* __restrict__ z,
                                                    _Float16* __restrict__ zh) {
  int i = blockIdx.x * 256 + threadIdx.x;
  float4 v = ((const float4*)z)[i];
  union { _Float16 h[4]; uint2 u; } p;
  p.h[0] = (_Float16)v.x; p.h[1] = (_Float16)v.y;
  p.h[2] = (_Float16)v.z; p.h[3] = (_Float16)v.w;
  ((uint2*)zh)[i] = p.u;
}

// ---- Phase 1: 128x128 MFMA tiles; double-buffered BK=32 pipeline ----
// LDS tile: [128 rows][32 halfs] = 64B/row, linear. Bank map: 16B slot s of
// row r sits on banks s*4..s*4+3 of half (r&1). Storage rule (conflict-free):
//   storage[row][s] = logical[row][s ^ ((row>>1)&3)]
// -> even rows sweep all 4 slots (2-way free), same for odd. gload_lds writes
// linearly (wave-uniform base + lane*16), so the SOURCE carries the inverse
// swizzle; ds_read applies the same XOR. Key uses (row>>1)&3 (R10 fix; R9's
// row&3 left even rows on 2 slots -> 4-way conflicts, 11x counter surge).
// 8 waves, 2x4 grid: wave (wm,wn) owns rows [wm*64,+64) x cols [wn*32,+32).
template <bool ZH>
__global__ __launch_bounds__(512, 4) void vq_mfma_kernel(
    const float* __restrict__ z, const _Float16* __restrict__ zh,
    const _Float16* __restrict__ chs, const float* __restrict__ csq,
    unsigned* __restrict__ cand_g, int* __restrict__ cnt_g) {
  __shared__ __align__(16) _Float16 Ah0[128 * 32];  // 8 KB each
  __shared__ __align__(16) _Float16 Ah1[128 * 32];
  __shared__ __align__(16) _Float16 Bh0[128 * 32];
  __shared__ __align__(16) _Float16 Bh1[128 * 32];
  __shared__ unsigned rowmin_u[128];   // key = float_as_uint(delta + 4.0f) > 0
  __shared__ int cnt[128];
  __shared__ unsigned char dropped[128];
  __shared__ unsigned cand[128 * CAND];             // 16 KB

  const int tid  = threadIdx.x;
  const int seg  = blockIdx.x & (NSEG - 1);
  const int m0   = (blockIdx.x >> 2) * 128;
  const int nt0  = seg * SEGC;
  const int wave = tid >> 6, lane = tid & 63;
  const int wm = wave >> 2, wn = wave & 3;     // 2x4 wave grid of 64x32
  const int q = lane >> 4, r = lane & 15;

  // staging geometry: wave stages rows [wave*16,+16); lane -> (row, 16B slot)
  const int srow = lane >> 2;                  // row within wave strip
  const int scol = (((lane & 3) ^ ((srow >> 1) & 3)) << 4);  // inverse swizzle
  const int rdoff = ((q << 4) ^ (((r >> 1) & 3) << 4));      // read-side XOR

  if (tid < 128) { rowmin_u[tid] = 0x7f800000u; cnt[tid] = 0; dropped[tid] = 0; }

  // ---- stage helpers (dest pointers wave-uniform; HW adds lane*16) ----
  auto stageA = [&](_Float16* Adst, int kc2) {
    if (ZH) {
      gload16((const char*)zh +
                  ((size_t)(m0 + wave * 16 + srow) * DIMS + kc2 * 32) * 2 + scol,
              (char*)Adst + wave * 1024);
    } else {   // convert-on-the-fly, swizzled VGPR store; 512 thr = 512 chunks
      const int rw = tid >> 2, cs = tid & 3;
      const float* src = z + (size_t)(m0 + rw) * DIMS + kc2 * 32 +
                         ((cs ^ ((rw >> 1) & 3)) << 3);
      float4 v0 = ((const float4*)src)[0], v1 = ((const float4*)src)[1];
      union { _Float16 h[8]; uint4 u; } p;
      p.h[0] = (_Float16)v0.x; p.h[1] = (_Float16)v0.y;
      p.h[2] = (_Float16)v0.z; p.h[3] = (_Float16)v0.w;
      p.h[4] = (_Float16)v1.x; p.h[5] = (_Float16)v1.y;
      p.h[6] = (_Float16)v1.z; p.h[7] = (_Float16)v1.w;
      *(uint4*)((char*)Adst + rw * 64 + cs * 16) = p.u;
    }
  };
  auto stageB = [&](_Float16* Bdst, int nt2, int kc2) {
    gload16((const char*)chs +
                ((size_t)(nt2 + wave * 16 + srow) * DIMS + kc2 * 32) * 2 + scol,
            (char*)Bdst + wave * 1024);
  };

  f32x4 acc[4][2];
  // prologue: stage (t=0, kc=0) into buffer 0
  stageA(Ah0, 0);
  stageB(Bh0, nt0, 0);
  __syncthreads();   // drains vmcnt(0): buffer 0 ready (also covers LDS init)

  for (int t = 0; t < NT; ++t) {
    const int nt = nt0 + t * 128;
    #pragma unroll
    for (int mf = 0; mf < 4; ++mf)
      #pragma unroll
      for (int nf = 0; nf < 2; ++nf) acc[mf][nf] = (f32x4){0.f, 0.f, 0.f, 0.f};

    #pragma unroll 1
    for (int kc = 0; kc < NKC; kc += 2) {
      // ---- phase A: stage next into buf1, compute from buf0 ----
      {
        const int flat = t * NKC + kc + 1;
        if (flat < NT * NKC) {
          const int t2 = flat >> 4, kc2 = flat & 15;
          stageA(Ah1, kc2);
          stageB(Bh1, nt0 + t2 * 128, kc2);
        }
      }
      {
        half8 af[4], bf[2];
        #pragma unroll
        for (int mf = 0; mf < 4; ++mf)
          af[mf] = *(const half8*)((const char*)Ah0 +
                     (wm * 64 + mf * 16 + r) * 64 + rdoff);
        #pragma unroll
        for (int nf = 0; nf < 2; ++nf)
          bf[nf] = *(const half8*)((const char*)Bh0 +
                     (wn * 32 + nf * 16 + r) * 64 + rdoff);
        #pragma unroll
        for (int mf = 0; mf < 4; ++mf)
          #pragma unroll
          for (int nf = 0; nf < 2; ++nf)
            acc[mf][nf] = __builtin_amdgcn_mfma_f32_16x16x32_f16(
                af[mf], bf[nf], acc[mf][nf], 0, 0, 0);
      }
      __syncthreads();   // vmcnt(0) drain covered by the MFMA phase above
      // ---- phase B: stage next into buf0, compute from buf1 ----
      {
        const int flat = t * NKC + kc + 2;
        if (flat < NT * NKC) {
          const int t2 = flat >> 4, kc2 = flat & 15;
          stageA(Ah0, kc2);
          stageB(Bh0, nt0 + t2 * 128, kc2);
        }
      }
      {
        half8 af[4], bf[2];
        #pragma unroll
        for (int mf = 0; mf < 4; ++mf)
          af[mf] = *(const half8*)((const char*)Ah1 +
                     (wm * 64 + mf * 16 + r) * 64 + rdoff);
        #pragma unroll
        for (int nf = 0; nf < 2; ++nf)
          bf[nf] = *(const half8*)((const char*)Bh1 +
                     (wn * 32 + nf * 16 + r) * 64 + rdoff);
        #pragma unroll
        for (int mf = 0; mf < 4; ++mf)
          #pragma unroll
          for (int nf = 0; nf < 2; ++nf)
            acc[mf][nf] = __builtin_amdgcn_mfma_f32_16x16x32_f16(
                af[mf], bf[nf], acc[mf][nf], 0, 0, 0);
      }
      __syncthreads();
    }

    // ---- epilogue on delta = fl(csq - acc*2^-10)  (== sv - zsq, tiny mag,
    //      so fp32 rounding ~1e-8 and fp16 storage ~3e-5 -- margin-safe).
    //      C/D layout: row=q*4+reg, col=r.
    float cs[2];
    #pragma unroll
    for (int nf = 0; nf < 2; ++nf) cs[nf] = csq[nt + wn * 32 + nf * 16 + r];
    float m4[4][4];      // [mf][reg] lane-local min over nf
    #pragma unroll
    for (int mf = 0; mf < 4; ++mf)
      #pragma unroll
      for (int reg = 0; reg < 4; ++reg) {
        float mn = INFINITY;
        #pragma unroll
        for (int nf = 0; nf < 2; ++nf)
          mn = fminf(mn, __fmaf_rn(-0.0009765625f, acc[mf][nf][reg], cs[nf]));
        m4[mf][reg] = mn;
      }
    #pragma unroll
    for (int mf = 0; mf < 4; ++mf)
      #pragma unroll
      for (int reg = 0; reg < 4; ++reg) {
        float v = m4[mf][reg];
        v = fminf(v, __shfl_xor(v, 1, 64));
        v = fminf(v, __shfl_xor(v, 2, 64));
        v = fminf(v, __shfl_xor(v, 4, 64));
        v = fminf(v, __shfl_xor(v, 8, 64));
        m4[mf][reg] = v;
      }
    if (r == 0) {
      #pragma unroll
      for (int mf = 0; mf < 4; ++mf)
        #pragma unroll
        for (int reg = 0; reg < 4; ++reg)
          atomicMin(&rowmin_u[wm * 64 + mf * 16 + q * 4 + reg],
                    __float_as_uint(m4[mf][reg] + 4.0f));  // delta+4 > 0 always
    }
    __syncthreads();   // tile-min includes ALL waves before thresholding
    #pragma unroll
    for (int mf = 0; mf < 4; ++mf)
      #pragma unroll
      for (int reg = 0; reg < 4; ++reg) {
        const int row = wm * 64 + mf * 16 + q * 4 + reg;
        float thr = __uint_as_float(rowmin_u[row]) - 4.0f + MARGIN;
        #pragma unroll
        for (int nf = 0; nf < 2; ++nf) {
          float d = __fmaf_rn(-0.0009765625f, acc[mf][nf][reg], cs[nf]);
          if (d <= thr) {
            int slot = atomicAdd(&cnt[row], 1);
            if (slot < CAND)
              cand[row * CAND + slot] = pack_ds(d, nt + wn * 32 + nf * 16 + r);
          }
        }
      }
    // ---- periodic compaction: re-filter vs the tightened min so the raw
    //      counter never creeps past CAND; drop flag only on a real discard.
    if ((t & 1) == 1 || t == (NT - 1)) {
      __syncthreads();   // all appends for this tile visible
      if (tid < 128) {
        const int raw = cnt[tid];
        const int m = raw < CAND ? raw : CAND;
        if (raw > CAND) dropped[tid] = 1;
        const float thr = __uint_as_float(rowmin_u[tid]) - 4.0f + MARGIN;
        int k = 0;
        for (int i = 0; i < m; ++i) {
          unsigned e = cand[tid * CAND + i];
          if (unpack_d(e) <= thr) cand[tid * CAND + k++] = e;
        }
        cnt[tid] = k;
      }
      __syncthreads();
    }
  }
  __syncthreads();
  if (tid < 128)
    cnt_g[(size_t)seg * N_ROWS + m0 + tid] = dropped[tid] ? (CAND + 1) : cnt[tid];
  for (int i = tid; i < 128 * CAND; i += 512)
    cand_g[((size_t)seg * N_ROWS + m0 + i / CAND) * CAND + (i % CAND)] = cand[i];
}

// ---- exact bitwise-np score (R2-verified): dual-panel seq FMA chain ----
__device__ __forceinline__ float exact_q(const float* zr, const float* cr,
                                         float zsr, float csr) {
  float s1 = 0.f;
  for (int k = 0; k < 384; k += 8) {
    float4 a0 = *(const float4*)(zr + k), a1 = *(const float4*)(zr + k + 4);
    float4 b0 = *(const float4*)(cr + k), b1 = *(const float4*)(cr + k + 4);
    s1 = __fmaf_rn(a0.x, b0.x, s1); s1 = __fmaf_rn(a0.y, b0.y, s1);
    s1 = __fmaf_rn(a0.z, b0.z, s1); s1 = __fmaf_rn(a0.w, b0.w, s1);
    s1 = __fmaf_rn(a1.x, b1.x, s1); s1 = __fmaf_rn(a1.y, b1.y, s1);
    s1 = __fmaf_rn(a1.z, b1.z, s1); s1 = __fmaf_rn(a1.w, b1.w, s1);
  }
  float s2 = 0.f;
  for (int k = 384; k < 512; k += 8) {
    float4 a0 = *(const float4*)(zr + k), a1 = *(const float4*)(zr + k + 4);
    float4 b0 = *(const float4*)(cr + k), b1 = *(const float4*)(cr + k + 4);
    s2 = __fmaf_rn(a0.x, b0.x, s2); s2 = __fmaf_rn(a0.y, b0.y, s2);
    s2 = __fmaf_rn(a0.z, b0.z, s2); s2 = __fmaf_rn(a0.w, b0.w, s2);
    s2 = __fmaf_rn(a1.x, b1.x, s2); s2 = __fmaf_rn(a1.y, b1.y, s2);
    s2 = __fmaf_rn(a1.w, b1.w, s2); s2 = __fmaf_rn(a1.z, b1.z, s2);
  }
  float cross = __fadd_rn(s1, s2);                 // fl(S1 + S2)
  return __fadd_rn(__fmaf_rn(-2.f, cross, zsr), csr);
}

// ---- Phase 2a: 4-segment merge. Global approx-min filter; singleton rows
//      decided free (competitors provably > margin away); rest -> pair list.
__global__ __launch_bounds__(256) void select_kernel(
    const int* __restrict__ cnt_g, const unsigned* __restrict__ cand_g,
    unsigned long long* __restrict__ best, unsigned* __restrict__ pairs,
    int* __restrict__ meta, int* __restrict__ ovf) {
  const int row  = blockIdx.x * 256 + threadIdx.x;
  const int lane = threadIdx.x & 63;
  int c[NSEG]; bool over = false; int tot = 0;
  #pragma unroll
  for (int s = 0; s < NSEG; ++s) {
    c[s] = cnt_g[(size_t)s * N_ROWS + row];
    if (c[s] > CAND) over = true;
    tot += c[s];
  }
  if (tot == 0) over = true;
  unsigned long long bkey = ~0ULL;
  int need = 0;
  float thr = 0.f;
  if (!over) {
    float gm = INFINITY;
    #pragma unroll
    for (int s = 0; s < NSEG; ++s)
      for (int j = 0; j < c[s]; ++j)
        gm = fminf(gm, unpack_d(cand_g[((size_t)s * N_ROWS + row) * CAND + j]));
    thr = gm + MARGIN;
    int k = 0; unsigned first = 0;
    #pragma unroll
    for (int s = 0; s < NSEG; ++s)
      for (int j = 0; j < c[s]; ++j) {
        unsigned e = cand_g[((size_t)s * N_ROWS + row) * CAND + j];
        if (unpack_d(e) <= thr) { if (k == 0) first = e; ++k; }
      }
    if (k == 1) bkey = (unsigned long long)(first & 0x1FFFu);  // decided
    else need = k;
  }
  best[row] = bkey;
  // wave-aggregated worklist allocation (1 atomic per wave)
  int pre = need;
  #pragma unroll
  for (int off = 1; off < 64; off <<= 1) {
    int v = __shfl_up(pre, off, 64);
    if (lane >= off) pre += v;
  }
  int wtot = __shfl(pre, 63, 64);
  int base = 0;
  if (lane == 63 && wtot > 0) base = atomicAdd(&meta[0], wtot);
  base = __shfl(base, 63, 64);
  const int my0 = base + pre - need;              // exclusive prefix
  bool row_ovf = over;
  if (need > 0) {
    if (my0 + need > PAIR_CAP) {
      row_ovf = true;                             // fallback handles this row
      for (int j = 0; j < need; ++j) {            // sentinel allocated slots
        int s = my0 + j;
        if (s < PAIR_CAP) pairs[s] = SENT;
      }
    } else {
      int kk = 0;
      #pragma unroll
      for (int s = 0; s < NSEG; ++s)
        for (int j = 0; j < c[s]; ++j) {
          unsigned e = cand_g[((size_t)s * N_ROWS + row) * CAND + j];
          if (unpack_d(e) <= thr)
            pairs[my0 + kk++] = ((unsigned)row << 13) | (e & 0x1FFFu);
        }
    }
  }
  if (row_ovf) { int s = atomicAdd(&meta[1], 1); ovf[s] = row; }
}

// ---- Phase 2b: dense exact rescore, one lane per (row,code) pair.
//      d2 > 0 always (zsq ~ 512) so uint order == float order; packed key
//      (q_bits<<32)|code -> atomicMin = argmin with lowest-index tie-break.
__global__ __launch_bounds__(256) void pairs_kernel(
    const float* __restrict__ z, const float* __restrict__ cb,
    const float* __restrict__ zsq, const float* __restrict__ csq,
    const unsigned* __restrict__ pairs, const int* __restrict__ meta,
    unsigned long long* __restrict__ best) {
  int n = meta[0];
  if (n > PAIR_CAP) n = PAIR_CAP;
  const int i = blockIdx.x * 256 + threadIdx.x;
  if (i >= n) return;
  const unsigned p = pairs[i];
  if (p == SENT) return;                          // unfilled overflow slot
  const int row = (int)(p >> 13), code = (int)(p & 8191u);
  const float qv = exact_q(z + (size_t)row * DIMS, cb + (size_t)code * DIMS,
                           zsq[row], csq[code]);
  const unsigned long long key =
      ((unsigned long long)__float_as_uint(qv) << 32) | (unsigned)code;
  atomicMin(&best[row], key);
}

// ---- Phase 2c: overflow net, one BLOCK per row.
//      Pass A: coalesced approx scan (8-lane groups, fp32 tree dot), scores
//              to LDS, block min.  Pass B: exact_q within min + 5e-4.
__global__ __launch_bounds__(256) void fallback_kernel(
    const float* __restrict__ z, const float* __restrict__ cb,
    const float* __restrict__ zsq, const float* __restrict__ csq,
    const int* __restrict__ ovf, const int* __restrict__ meta,
    unsigned long long* __restrict__ best) {
  __shared__ float sc[KCODES];     // 32 KB approx deltas
  __shared__ float zrow[DIMS];     // 2 KB
  __shared__ unsigned bmin;
  const int n = meta[1];
  for (int wi = blockIdx.x; wi < n; wi += gridDim.x) {
    const int row = ovf[wi];
    for (int i = threadIdx.x; i < DIMS; i += 256)
      zrow[i] = z[(size_t)row * DIMS + i];
    if (threadIdx.x == 0) bmin = 0x7f800000u;
    __syncthreads();
    const int g = threadIdx.x >> 3;       // 32 groups of 8 lanes
    const int j = threadIdx.x & 7;
    float lmin = INFINITY;
    for (int c = g; c < KCODES; c += 32) {
      const float* cr = cb + (size_t)c * DIMS;
      float s = 0.f;
      #pragma unroll
      for (int i = 0; i < 16; ++i) {      // 64 dims per lane, 128B/group/step
        float4 a = *(const float4*)(&zrow[j * 4 + i * 32]);
        float4 b = *(const float4*)(cr + j * 4 + i * 32);
        s = __fmaf_rn(a.x, b.x, s); s = __fmaf_rn(a.y, b.y, s);
        s = __fmaf_rn(a.z, b.z, s); s = __fmaf_rn(a.w, b.w, s);
      }
      s += __shfl_xor(s, 1, 64);          // butterfly within 8-lane group
      s += __shfl_xor(s, 2, 64);
      s += __shfl_xor(s, 4, 64);
      float d = __fmaf_rn(-2.f, s, csq[c]);
      if (j == 0) sc[c] = d;
      lmin = fminf(lmin, d);
    }
    atomicMin(&bmin, __float_as_uint(lmin + 4.0f));   // delta+4 > 0
    __syncthreads();
    const float thr = __uint_as_float(bmin) - 4.0f + 5e-4f;
    const float zsr = zsq[row];
    const float* zr = z + (size_t)row * DIMS;
    for (int c = threadIdx.x; c < KCODES; c += 256) {
      if (sc[c] <= thr) {
        float qv = exact_q(zr, cb + (size_t)c * DIMS, zsr, csq[c]);
        unsigned long long key =
            ((unsigned long long)__float_as_uint(qv) << 32) | (unsigned)c;
        atomicMin(&best[row], key);
      }
    }
    __syncthreads();   // before next row reuses LDS
  }
}

// ---- Phase 2d: coalesced gather of winner rows + index write ----
__global__ __launch_bounds__(256) void gather_kernel(
    const float* __restrict__ cb, const unsigned long long* __restrict__ best,
    float* __restrict__ zq, float* __restrict__ idx_out) {
  const int wave = threadIdx.x >> 6, lane = threadIdx.x & 63;
  const int row = blockIdx.x * 4 + wave;
  const int code = (int)(unsigned)(best[row] & 0xFFFFFFFFu);
  if (lane == 0) idx_out[row] = (float)code;
  const float4* cbv = (const float4*)(cb + (size_t)code * DIMS);
  float4* zqv = (float4*)(zq + (size_t)row * DIMS);
  zqv[lane]      = cbv[lane];
  zqv[lane + 64] = cbv[lane + 64];
}

extern "C" void kernel_launch(void* const* d_in, const int* in_sizes, int n_in,
                              void* d_out, int out_size, void* d_ws, size_t ws_size,
                              hipStream_t stream) {
  const float* z  = (const float*)d_in[0];
  const float* cb = (const float*)d_in[1];
  float* out     = (float*)d_out;
  float* zq      = out;
  float* idx_out = out + (size_t)N_ROWS * DIMS;

  // workspace layout (all chunks 256B-multiples)
  char* w = (char*)d_ws;
  _Float16* cbh = (_Float16*)w;            w += (size_t)KCODES * DIMS * 2;   // 8 MB
  float* zsq = (float*)w;                  w += (size_t)N_ROWS * 4;          // 128 KB
  float* csq = (float*)w;                  w += (size_t)KCODES * 4;          // 32 KB
  int* cnt_g = (int*)w;                    w += (size_t)NSEG * N_ROWS * 4;   // 512 KB
  unsigned* cand_g = (unsigned*)w;         w += (size_t)NSEG * N_ROWS * CAND * 4; // 16MB
  unsigned long long* best = (unsigned long long*)w; w += (size_t)N_ROWS * 8;  // 256 KB
  unsigned* pairs = (unsigned*)w;          w += (size_t)PAIR_CAP * 4;        // 1 MB
  int* meta = (int*)w;                     w += 256;                         // counters
  int* ovf = (int*)w;                      w += (size_t)N_ROWS * 4;          // 128 KB
  _Float16* zh = (_Float16*)w;             w += (size_t)N_ROWS * DIMS * 2;   // 32 MB
  bool use_zh = ((size_t)(w - (char*)d_ws) <= ws_size);

  hipMemsetAsync(meta, 0, 256, stream);

  rowsq_kernel<<<N_ROWS / 4, 256, 0, stream>>>(z, zsq);
  rowsq_kernel<<<KCODES / 4, 256, 0, stream>>>(cb, csq);
  cvt_cb_kernel<<<KCODES * DIMS / 1024, 256, 0, stream>>>(cb, cbh);
  if (use_zh) {
    cvt_z_kernel<<<N_ROWS * DIMS / 1024, 256, 0, stream>>>(z, zh);
    vq_mfma_kernel<true><<<(N_ROWS / 128) * NSEG, 512, 0, stream>>>(
        z, zh, cbh, csq, cand_g, cnt_g);
  } else {
    vq_mfma_kernel<false><<<(N_ROWS / 128) * NSEG, 512, 0, stream>>>(
        z, nullptr, cbh, csq, cand_g, cnt_g);
  }
  select_kernel<<<N_ROWS / 256, 256, 0, stream>>>(cnt_g, cand_g, best, pairs,
                                                  meta, ovf);
  pairs_kernel<<<PAIR_CAP / 256, 256, 0, stream>>>(z, cb, zsq, csq, pairs,
                                                   meta, best);
  fallback_kernel<<<512, 256, 0, stream>>>(z, cb, zsq, csq, ovf, meta, best);
  gather_kernel<<<N_ROWS / 4, 256, 0, stream>>>(cb, best, zq, idx_out);
}